// Round 1
// baseline (504.703 us; speedup 1.0000x reference)
//
#include <hip/hip_runtime.h>
#include <math.h>

#define DM 512          // d_model
#define NQ 16           // num output queries
#define NG (NQ + 1)     // 16 score rows + 1 pooled-v row

__device__ __forceinline__ float wave_reduce_sum(float v) {
    #pragma unroll
    for (int off = 32; off > 0; off >>= 1) v += __shfl_xor(v, off, 64);
    return v;
}
__device__ __forceinline__ float wave_reduce_max(float v) {
    #pragma unroll
    for (int off = 32; off > 0; off >>= 1) v = fmaxf(v, __shfl_xor(v, off, 64));
    return v;
}

// --- 1. PE table, transposed [d][n], plus per-n sum / sumsq of PE row ------
__global__ void pe_kernel(float* PET, float* peS, float* peQ, int N) {
    int n = blockIdx.x * 64 + threadIdx.x;
    if (n >= N) return;
    float p = (float)(N - 1 - n);               // reversed PE, last N positions
    float s1 = 0.f, s2 = 0.f;
    const float c = -logf(10000.f) / (float)DM;
    for (int j = 0; j < DM / 2; ++j) {
        float w = expf((float)(2 * j) * c);
        float ang = p * w;
        float sv = sinf(ang), cv = cosf(ang);
        PET[(size_t)(2 * j) * N + n] = sv;
        PET[(size_t)(2 * j + 1) * N + n] = cv;
        s1 += sv + cv;
        s2 += sv * sv + cv * cv;
    }
    peS[n] = s1;
    peQ[n] = s2;
}

// --- 2. LayerNorm of query*scale  (16 rows, one wave per row) --------------
__global__ void qln_kernel(const float* query, const float* lnw, const float* lnb,
                           float* q_ln) {
    int q = threadIdx.x >> 6;
    int lane = threadIdx.x & 63;
    const float scale = 22.627416997969522f;    // sqrt(512)
    float vals[8], s = 0.f, s2 = 0.f;
    #pragma unroll
    for (int i = 0; i < 8; ++i) {
        float x = query[q * DM + i * 64 + lane] * scale;
        vals[i] = x; s += x; s2 += x * x;
    }
    s = wave_reduce_sum(s); s2 = wave_reduce_sum(s2);
    float m = s * (1.f / DM);
    float var = s2 * (1.f / DM) - m * m;
    float rstd = rsqrtf(var + 1e-5f);
    #pragma unroll
    for (int i = 0; i < 8; ++i) {
        int d = i * 64 + lane;
        q_ln[q * DM + d] = (vals[i] - m) * rstd * lnw[d] + lnb[d];
    }
}

// --- 3. qh[q][e] = q_ln[q] . Wq[e] + bq[e] ---------------------------------
__global__ void qh_kernel(const float* q_ln, const float* Wq, const float* bq,
                          float* qh) {
    int gid = blockIdx.x * 256 + threadIdx.x;   // 16*512 threads
    int q = gid >> 9, e = gid & 511;
    const float4* wrow = (const float4*)(Wq + (size_t)e * DM);
    const float4* qrow = (const float4*)(q_ln + (size_t)q * DM);
    float acc = 0.f;
    for (int i = 0; i < DM / 4; ++i) {
        float4 w = wrow[i], x = qrow[i];
        acc += w.x * x.x + w.y * x.y + w.z * x.z + w.w * x.w;
    }
    qh[q * DM + e] = acc + bq[e];
}

// --- 4. q_tilde[q][d] = sum_e qh[q][e]*Wk[e][d];  wv[d] = sum_e Wo[e]*Wv[e][d]
//        A[g][d] = coeff * ln_lat_w[d]   (g=16 row is wv) ---------------------
__global__ void qt_kernel(const float* qh, const float* Wk, const float* Wo,
                          const float* Wv, const float* lnw,
                          float* qt, float* A, float* wvout) {
    int gid = blockIdx.x * 256 + threadIdx.x;   // 17*512 threads
    int g = gid >> 9, d = gid & 511;
    float acc = 0.f;
    if (g < NQ) {
        for (int e = 0; e < DM; ++e) acc += qh[g * DM + e] * Wk[(size_t)e * DM + d];
        qt[g * DM + d] = acc;
    } else {
        for (int e = 0; e < DM; ++e) acc += Wo[e] * Wv[(size_t)e * DM + d];
        wvout[d] = acc;
    }
    A[g * DM + d] = acc * lnw[d];
}

// --- 5. small reduction constants ------------------------------------------
__global__ void consts_kernel(const float* A, const float* qt, const float* qh,
                              const float* wv, const float* lnb, const float* bk,
                              const float* Wo, const float* bv, float* consts) {
    int t = threadIdx.x;
    if (t < NQ) {
        float sa = 0.f, sc = 0.f, qb = 0.f;
        for (int d = 0; d < DM; ++d) { sa += A[t * DM + d]; sc += qt[t * DM + d] * lnb[d]; }
        for (int e = 0; e < DM; ++e) qb += qh[t * DM + e] * bk[e];
        consts[t] = sa;              // sumA_q
        consts[16 + t] = sc + qb;    // SC_q = C_q + qh.bk
    } else if (t == NQ) {
        float sa = 0.f, cv = 0.f, bvo = 0.f;
        for (int d = 0; d < DM; ++d) { sa += A[NQ * DM + d]; cv += wv[d] * lnb[d]; }
        for (int e = 0; e < DM; ++e) bvo += Wo[e] * bv[e];
        consts[32] = sa;             // sumAv
        consts[33] = cv + bvo;       // CvTot (bo added in phase 2)
    }
}

// --- 6. peA[g][n] = sum_d A[g][d] * PE[n][d] -------------------------------
__global__ void peA_kernel(const float* A, const float* PET, float* peA, int N) {
    int g = blockIdx.y;
    int n = blockIdx.x * 256 + threadIdx.x;
    float acc = 0.f;
    for (int d = 0; d < DM; ++d) acc += A[g * DM + d] * PET[(size_t)d * N + n];
    peA[(size_t)g * N + n] = acc;
}

// --- 7. main streaming kernel: lane=column n, 4 waves split d --------------
__launch_bounds__(256, 4)
__global__ void main_kernel(const float* __restrict__ latents,
                            const float* __restrict__ PET,
                            const float* __restrict__ A,
                            const float* __restrict__ peA,
                            const float* __restrict__ peS,
                            const float* __restrict__ peQ,
                            const float* __restrict__ consts,
                            float* __restrict__ scores,
                            float* __restrict__ vbuf, int N) {
    int b = blockIdx.y;
    int lane = threadIdx.x & 63;
    int wv = threadIdx.x >> 6;
    int n = blockIdx.x * 64 + lane;
    const float scale = 22.627416997969522f;    // sqrt(512)

    const float* lat = latents + (size_t)b * DM * N + n;

    float acc[NG];
    #pragma unroll
    for (int i = 0; i < NG; ++i) acc[i] = 0.f;
    float S1 = 0.f, S2 = 0.f, Sx = 0.f;

    int d0 = wv * (DM / 4);
    #pragma unroll 4
    for (int dd = 0; dd < DM / 4; ++dd) {
        int d = d0 + dd;
        float x = lat[(size_t)d * N];
        float pe = PET[(size_t)d * N + n];
        S1 += x; S2 += x * x; Sx += x * pe;
        #pragma unroll
        for (int q = 0; q < NQ; ++q) acc[q] += A[q * DM + d] * x;
        acc[NQ] += A[NQ * DM + d] * x;
    }

    __shared__ float red[4][NG + 3][64];
    red[wv][0][lane] = S1;
    red[wv][1][lane] = S2;
    red[wv][2][lane] = Sx;
    #pragma unroll
    for (int i = 0; i < NG; ++i) red[wv][3 + i][lane] = acc[i];
    __syncthreads();
    if (wv != 0) return;

    float tot[NG + 3];
    #pragma unroll
    for (int i = 0; i < NG + 3; ++i)
        tot[i] = red[0][i][lane] + red[1][i][lane] + red[2][i][lane] + red[3][i][lane];

    float s1 = tot[0], s2 = tot[1], sx = tot[2];
    float m = (scale * s1 + peS[n]) * (1.f / DM);
    float ex2 = (scale * scale * s2 + 2.f * scale * sx + peQ[n]) * (1.f / DM);
    float rstd = rsqrtf(ex2 - m * m + 1e-5f);

    float sumAv = consts[32], CvT = consts[33];
    float v = rstd * (scale * tot[3 + NQ] + peA[(size_t)NQ * N + n] - m * sumAv) + CvT;
    vbuf[(size_t)b * N + n] = v;

    const float isd = 0.044194173824159216f;    // 1/sqrt(512)
    #pragma unroll
    for (int q = 0; q < NQ; ++q) {
        float sc = (rstd * (scale * tot[3 + q] + peA[(size_t)q * N + n] - m * consts[q])
                    + consts[16 + q]) * isd;
        scores[((size_t)b * NQ + q) * N + n] = sc;
    }
}

// --- 8. softmax over n + attention-weight output + pooled logits -----------
__global__ void softmax_kernel(const float* __restrict__ scores,
                               const float* __restrict__ vbuf,
                               const float* __restrict__ query_mask,
                               const float* __restrict__ bo,
                               float* __restrict__ out_logits,
                               float* __restrict__ out_attn, int N) {
    int r = blockIdx.x;                 // b*NQ + q
    int b = r >> 4;
    int lane = threadIdx.x;
    float* attn_row = out_attn + (size_t)r * N;
    float qm = query_mask[r];
    if (qm == 0.f) {                    // fully masked row: uniform weights, wiped logits
        float u = 1.f / (float)N;
        for (int i = 0; i < N / 64; ++i) attn_row[i * 64 + lane] = u;
        if (lane == 0) out_logits[r] = bo[0];
        return;
    }
    const float* srow = scores + (size_t)r * N;
    float sv[8];
    float mx = -1e30f;
    for (int i = 0; i < N / 64; ++i) { sv[i] = srow[i * 64 + lane]; mx = fmaxf(mx, sv[i]); }
    mx = wave_reduce_max(mx);
    float sum = 0.f;
    for (int i = 0; i < N / 64; ++i) { sv[i] = expf(sv[i] - mx); sum += sv[i]; }
    sum = wave_reduce_sum(sum);
    float inv = 1.f / sum;
    const float* vrow = vbuf + (size_t)b * N;
    float lp = 0.f;
    for (int i = 0; i < N / 64; ++i) {
        float w = sv[i] * inv;
        attn_row[i * 64 + lane] = w;
        lp += w * vrow[i * 64 + lane];
    }
    lp = wave_reduce_sum(lp);
    if (lane == 0) out_logits[r] = lp + bo[0];
}

extern "C" void kernel_launch(void* const* d_in, const int* in_sizes, int n_in,
                              void* d_out, int out_size, void* d_ws, size_t ws_size,
                              hipStream_t stream) {
    const float* latents    = (const float*)d_in[0];
    const float* query_mask = (const float*)d_in[1];
    const float* query      = (const float*)d_in[2];
    const float* ln_lat_w   = (const float*)d_in[3];
    const float* ln_lat_b   = (const float*)d_in[4];
    const float* ln_q_w     = (const float*)d_in[5];
    const float* ln_q_b     = (const float*)d_in[6];
    const float* Wq         = (const float*)d_in[7];
    const float* bq         = (const float*)d_in[8];
    const float* Wk         = (const float*)d_in[9];
    const float* bk         = (const float*)d_in[10];
    const float* Wv         = (const float*)d_in[11];
    const float* bv         = (const float*)d_in[12];
    const float* Wo         = (const float*)d_in[13];
    const float* bo         = (const float*)d_in[14];

    int B = in_sizes[1] / NQ;
    int N = in_sizes[0] / (DM * B);

    float* ws = (float*)d_ws;
    size_t off = 0;
    float* PET    = ws + off; off += (size_t)DM * N;
    float* peS    = ws + off; off += N;
    float* peQ    = ws + off; off += N;
    float* q_ln   = ws + off; off += NQ * DM;
    float* qh     = ws + off; off += NQ * DM;
    float* qt     = ws + off; off += NQ * DM;
    float* A      = ws + off; off += NG * DM;
    float* wv     = ws + off; off += DM;
    float* peA    = ws + off; off += (size_t)NG * N;
    float* consts = ws + off; off += 64;
    float* scores = ws + off; off += (size_t)B * NQ * N;
    float* vbuf   = ws + off; off += (size_t)B * N;

    float* out_logits = (float*)d_out;
    float* out_attn   = out_logits + (size_t)B * NQ;

    pe_kernel<<<N / 64, 64, 0, stream>>>(PET, peS, peQ, N);
    qln_kernel<<<1, NQ * 64, 0, stream>>>(query, ln_q_w, ln_q_b, q_ln);
    qh_kernel<<<NQ * DM / 256, 256, 0, stream>>>(q_ln, Wq, bq, qh);
    qt_kernel<<<NG * DM / 256, 256, 0, stream>>>(qh, Wk, Wo, Wv, ln_lat_w, qt, A, wv);
    consts_kernel<<<1, 64, 0, stream>>>(A, qt, qh, wv, ln_lat_b, bk, Wo, bv, consts);
    dim3 gpea(N / 256, NG);
    peA_kernel<<<gpea, 256, 0, stream>>>(A, PET, peA, N);
    dim3 gmain(N / 64, B);
    main_kernel<<<gmain, 256, 0, stream>>>(latents, PET, A, peA, peS, peQ, consts,
                                           scores, vbuf, N);
    softmax_kernel<<<B * NQ, 64, 0, stream>>>(scores, vbuf, query_mask, bo,
                                              out_logits, out_attn, N);
}

// Round 2
// 422.767 us; speedup vs baseline: 1.1938x; 1.1938x over previous
//
#include <hip/hip_runtime.h>
#include <math.h>

#define DM 512          // d_model
#define NQ 16           // num output queries
#define NG (NQ + 1)     // 16 score rows + 1 pooled-v row

__device__ __forceinline__ float wave_reduce_sum(float v) {
    #pragma unroll
    for (int off = 32; off > 0; off >>= 1) v += __shfl_xor(v, off, 64);
    return v;
}
__device__ __forceinline__ float wave_reduce_max(float v) {
    #pragma unroll
    for (int off = 32; off > 0; off >>= 1) v = fmaxf(v, __shfl_xor(v, off, 64));
    return v;
}

// --- 1. PE table, transposed [d][n]. grid (N/64, 16), block 256 ------------
// thread: lane = n (coalesced stores), wave w + u cover 4 j's each.
__global__ void pe_kernel(float* __restrict__ PET, int N) {
    int lane = threadIdx.x & 63;
    int w = threadIdx.x >> 6;
    int n = blockIdx.x * 64 + lane;
    float p = (float)(N - 1 - n);               // reversed PE
    const float c = -logf(10000.f) / (float)DM;
    int jbase = blockIdx.y * 16 + w * 4;
    #pragma unroll
    for (int u = 0; u < 4; ++u) {
        int j = jbase + u;
        float wj = expf((float)(2 * j) * c);
        float ang = p * wj;
        PET[(size_t)(2 * j) * N + n] = sinf(ang);
        PET[(size_t)(2 * j + 1) * N + n] = cosf(ang);
    }
}

// --- 2. LayerNorm of query*scale  (16 rows, one wave per row) --------------
__global__ void qln_kernel(const float* query, const float* lnw, const float* lnb,
                           float* q_ln) {
    int q = threadIdx.x >> 6;
    int lane = threadIdx.x & 63;
    const float scale = 22.627416997969522f;    // sqrt(512)
    float vals[8], s = 0.f, s2 = 0.f;
    #pragma unroll
    for (int i = 0; i < 8; ++i) {
        float x = query[q * DM + i * 64 + lane] * scale;
        vals[i] = x; s += x; s2 += x * x;
    }
    s = wave_reduce_sum(s); s2 = wave_reduce_sum(s2);
    float m = s * (1.f / DM);
    float var = s2 * (1.f / DM) - m * m;
    float rstd = rsqrtf(var + 1e-5f);
    #pragma unroll
    for (int i = 0; i < 8; ++i) {
        int d = i * 64 + lane;
        q_ln[q * DM + d] = (vals[i] - m) * rstd * lnw[d] + lnb[d];
    }
}

// --- 3. qh[q][e] = q_ln[q] . Wq[e] + bq[e] ---------------------------------
__global__ void qh_kernel(const float* q_ln, const float* Wq, const float* bq,
                          float* qh) {
    int gid = blockIdx.x * 256 + threadIdx.x;   // 16*512 threads
    int q = gid >> 9, e = gid & 511;
    const float4* wrow = (const float4*)(Wq + (size_t)e * DM);
    const float4* qrow = (const float4*)(q_ln + (size_t)q * DM);
    float acc = 0.f;
    for (int i = 0; i < DM / 4; ++i) {
        float4 w = wrow[i], x = qrow[i];
        acc += w.x * x.x + w.y * x.y + w.z * x.z + w.w * x.w;
    }
    qh[q * DM + e] = acc + bq[e];
}

// --- 4. q_tilde[q][d] = sum_e qh[q][e]*Wk[e][d];  wv[d] = sum_e Wo[e]*Wv[e][d]
//        A[g][d] = coeff * ln_lat_w[d]   (g=16 row is wv) ------------------
__global__ void qt_kernel(const float* qh, const float* Wk, const float* Wo,
                          const float* Wv, const float* lnw,
                          float* qt, float* A, float* wvout) {
    int gid = blockIdx.x * 256 + threadIdx.x;   // 17*512 threads
    int g = gid >> 9, d = gid & 511;
    float acc = 0.f;
    if (g < NQ) {
        for (int e = 0; e < DM; ++e) acc += qh[g * DM + e] * Wk[(size_t)e * DM + d];
        qt[g * DM + d] = acc;
    } else {
        for (int e = 0; e < DM; ++e) acc += Wo[e] * Wv[(size_t)e * DM + d];
        wvout[d] = acc;
    }
    A[g * DM + d] = acc * lnw[d];
}

// --- 5. small reduction constants ------------------------------------------
__global__ void consts_kernel(const float* A, const float* qt, const float* qh,
                              const float* wv, const float* lnb, const float* bk,
                              const float* Wo, const float* bv, float* consts) {
    int t = threadIdx.x;
    if (t < NQ) {
        float sa = 0.f, sc = 0.f, qb = 0.f;
        for (int d = 0; d < DM; ++d) { sa += A[t * DM + d]; sc += qt[t * DM + d] * lnb[d]; }
        for (int e = 0; e < DM; ++e) qb += qh[t * DM + e] * bk[e];
        consts[t] = sa;              // sumA_q
        consts[16 + t] = sc + qb;    // SC_q = C_q + qh.bk
    } else if (t == NQ) {
        float sa = 0.f, cv = 0.f, bvo = 0.f;
        for (int d = 0; d < DM; ++d) { sa += A[NQ * DM + d]; cv += wv[d] * lnb[d]; }
        for (int e = 0; e < DM; ++e) bvo += Wo[e] * bv[e];
        consts[32] = sa;             // sumAv
        consts[33] = cv + bvo;       // CvTot (bo added in phase 2)
    }
}

// --- 6. peA[g][n] = sum_d A[g][d]*PE[n][d];  g=NG: peS, g=NG+1: peQ --------
__global__ void peA_kernel(const float* A, const float* PET, float* peA,
                           float* peS, float* peQ, int N) {
    int g = blockIdx.y;
    int n = blockIdx.x * 256 + threadIdx.x;
    float acc = 0.f;
    if (g < NG) {
        for (int d = 0; d < DM; ++d) acc += A[g * DM + d] * PET[(size_t)d * N + n];
        peA[(size_t)g * N + n] = acc;
    } else if (g == NG) {
        for (int d = 0; d < DM; ++d) acc += PET[(size_t)d * N + n];
        peS[n] = acc;
    } else {
        for (int d = 0; d < DM; ++d) {
            float v = PET[(size_t)d * N + n];
            acc += v * v;
        }
        peQ[n] = acc;
    }
}

// --- 7. main streaming kernel: lane=column n, 4 waves split d --------------
// Explicit register double-buffer (8 lat + 8 PET in flight, 16 loads/wave)
// so the wave is never load-latency serialized. A[] addressed via
// readfirstlane'd scalar index -> SMEM loads, off the vector-memory pipe.
__launch_bounds__(256, 4)
__global__ void main_kernel(const float* __restrict__ latents,
                            const float* __restrict__ PET,
                            const float* __restrict__ A,
                            const float* __restrict__ peA,
                            const float* __restrict__ peS,
                            const float* __restrict__ peQ,
                            const float* __restrict__ consts,
                            float* __restrict__ scores,
                            float* __restrict__ vbuf, int N) {
    int b = blockIdx.y;
    int lane = threadIdx.x & 63;
    int wv = threadIdx.x >> 6;
    int n = blockIdx.x * 64 + lane;
    const float scale = 22.627416997969522f;    // sqrt(512)

    int d0 = __builtin_amdgcn_readfirstlane(wv * (DM / 4));   // wave-uniform
    const float* lat = latents + (size_t)b * DM * N + (size_t)d0 * N + n;
    const float* pet = PET + (size_t)d0 * N + n;

    float acc[NG];
    #pragma unroll
    for (int i = 0; i < NG; ++i) acc[i] = 0.f;
    float S1 = 0.f, S2 = 0.f, Sx = 0.f;

    const int U = 8;                 // chunk size
    const int NC = (DM / 4) / U;     // 16 chunks of 8 d each
    float xb[2][U], pb[2][U];
    #pragma unroll
    for (int u = 0; u < U; ++u) {
        xb[0][u] = __builtin_nontemporal_load(&lat[(size_t)u * N]);
        pb[0][u] = pet[(size_t)u * N];
    }
    int cur = 0;
    for (int c = 0; c < NC; ++c) {
        int nxt = cur ^ 1;
        if (c + 1 < NC) {
            #pragma unroll
            for (int u = 0; u < U; ++u) {
                size_t dd = (size_t)((c + 1) * U + u) * N;
                xb[nxt][u] = __builtin_nontemporal_load(&lat[dd]);
                pb[nxt][u] = pet[dd];
            }
        }
        #pragma unroll
        for (int u = 0; u < U; ++u) {
            float x = xb[cur][u], pe = pb[cur][u];
            S1 += x; S2 = fmaf(x, x, S2); Sx = fmaf(x, pe, Sx);
            int d = d0 + c * U + u;              // fully scalar index
            #pragma unroll
            for (int q = 0; q < NG; ++q)
                acc[q] = fmaf(A[(size_t)q * DM + d], x, acc[q]);
        }
        cur = nxt;
    }

    __shared__ float red[4][NG + 3][64];
    red[wv][0][lane] = S1;
    red[wv][1][lane] = S2;
    red[wv][2][lane] = Sx;
    #pragma unroll
    for (int i = 0; i < NG; ++i) red[wv][3 + i][lane] = acc[i];
    __syncthreads();
    if (wv != 0) return;

    float tot[NG + 3];
    #pragma unroll
    for (int i = 0; i < NG + 3; ++i)
        tot[i] = red[0][i][lane] + red[1][i][lane] + red[2][i][lane] + red[3][i][lane];

    float s1 = tot[0], s2 = tot[1], sx = tot[2];
    float m = (scale * s1 + peS[n]) * (1.f / DM);
    float ex2 = (scale * scale * s2 + 2.f * scale * sx + peQ[n]) * (1.f / DM);
    float rstd = rsqrtf(ex2 - m * m + 1e-5f);

    float sumAv = consts[32], CvT = consts[33];
    float v = rstd * (scale * tot[3 + NQ] + peA[(size_t)NQ * N + n] - m * sumAv) + CvT;
    vbuf[(size_t)b * N + n] = v;

    const float isd = 0.044194173824159216f;    // 1/sqrt(512)
    #pragma unroll
    for (int q = 0; q < NQ; ++q) {
        float sc = (rstd * (scale * tot[3 + q] + peA[(size_t)q * N + n] - m * consts[q])
                    + consts[16 + q]) * isd;
        scores[((size_t)b * NQ + q) * N + n] = sc;
    }
}

// --- 8. softmax over n + attention-weight output + pooled logits -----------
__global__ void softmax_kernel(const float* __restrict__ scores,
                               const float* __restrict__ vbuf,
                               const float* __restrict__ query_mask,
                               const float* __restrict__ bo,
                               float* __restrict__ out_logits,
                               float* __restrict__ out_attn, int N) {
    int r = blockIdx.x;                 // b*NQ + q
    int b = r >> 4;
    int lane = threadIdx.x;
    float* attn_row = out_attn + (size_t)r * N;
    float qm = query_mask[r];
    if (qm == 0.f) {                    // fully masked row: uniform weights, wiped logits
        float u = 1.f / (float)N;
        for (int i = 0; i < N / 64; ++i) attn_row[i * 64 + lane] = u;
        if (lane == 0) out_logits[r] = bo[0];
        return;
    }
    const float* srow = scores + (size_t)r * N;
    float sv[8];
    float mx = -1e30f;
    for (int i = 0; i < N / 64; ++i) { sv[i] = srow[i * 64 + lane]; mx = fmaxf(mx, sv[i]); }
    mx = wave_reduce_max(mx);
    float sum = 0.f;
    for (int i = 0; i < N / 64; ++i) { sv[i] = expf(sv[i] - mx); sum += sv[i]; }
    sum = wave_reduce_sum(sum);
    float inv = 1.f / sum;
    const float* vrow = vbuf + (size_t)b * N;
    float lp = 0.f;
    for (int i = 0; i < N / 64; ++i) {
        float w = sv[i] * inv;
        attn_row[i * 64 + lane] = w;
        lp += w * vrow[i * 64 + lane];
    }
    lp = wave_reduce_sum(lp);
    if (lane == 0) out_logits[r] = lp + bo[0];
}

extern "C" void kernel_launch(void* const* d_in, const int* in_sizes, int n_in,
                              void* d_out, int out_size, void* d_ws, size_t ws_size,
                              hipStream_t stream) {
    const float* latents    = (const float*)d_in[0];
    const float* query_mask = (const float*)d_in[1];
    const float* query      = (const float*)d_in[2];
    const float* ln_lat_w   = (const float*)d_in[3];
    const float* ln_lat_b   = (const float*)d_in[4];
    const float* ln_q_w     = (const float*)d_in[5];
    const float* ln_q_b     = (const float*)d_in[6];
    const float* Wq         = (const float*)d_in[7];
    const float* bq         = (const float*)d_in[8];
    const float* Wk         = (const float*)d_in[9];
    const float* bk         = (const float*)d_in[10];
    const float* Wv         = (const float*)d_in[11];
    const float* bv         = (const float*)d_in[12];
    const float* Wo         = (const float*)d_in[13];
    const float* bo         = (const float*)d_in[14];

    int B = in_sizes[1] / NQ;
    int N = in_sizes[0] / (DM * B);

    float* ws = (float*)d_ws;
    size_t off = 0;
    float* PET    = ws + off; off += (size_t)DM * N;
    float* peS    = ws + off; off += N;
    float* peQ    = ws + off; off += N;
    float* q_ln   = ws + off; off += NQ * DM;
    float* qh     = ws + off; off += NQ * DM;
    float* qt     = ws + off; off += NQ * DM;
    float* A      = ws + off; off += NG * DM;
    float* wv     = ws + off; off += DM;
    float* peA    = ws + off; off += (size_t)NG * N;
    float* consts = ws + off; off += 64;
    float* scores = ws + off; off += (size_t)B * NQ * N;
    float* vbuf   = ws + off; off += (size_t)B * N;

    float* out_logits = (float*)d_out;
    float* out_attn   = out_logits + (size_t)B * NQ;

    dim3 gpe(N / 64, 16);
    pe_kernel<<<gpe, 256, 0, stream>>>(PET, N);
    qln_kernel<<<1, NQ * 64, 0, stream>>>(query, ln_q_w, ln_q_b, q_ln);
    qh_kernel<<<NQ * DM / 256, 256, 0, stream>>>(q_ln, Wq, bq, qh);
    qt_kernel<<<NG * DM / 256, 256, 0, stream>>>(qh, Wk, Wo, Wv, ln_lat_w, qt, A, wv);
    consts_kernel<<<1, 64, 0, stream>>>(A, qt, qh, wv, ln_lat_b, bk, Wo, bv, consts);
    dim3 gpea(N / 256, NG + 2);
    peA_kernel<<<gpea, 256, 0, stream>>>(A, PET, peA, peS, peQ, N);
    dim3 gmain(N / 64, B);
    main_kernel<<<gmain, 256, 0, stream>>>(latents, PET, A, peA, peS, peQ, consts,
                                           scores, vbuf, N);
    softmax_kernel<<<B * NQ, 64, 0, stream>>>(scores, vbuf, query_mask, bo,
                                              out_logits, out_attn, N);
}

// Round 3
// 282.980 us; speedup vs baseline: 1.7835x; 1.4940x over previous
//
#include <hip/hip_runtime.h>
#include <math.h>

#define DM 512          // d_model
#define NQ 16           // num output queries
#define NG (NQ + 1)     // 16 score rows + 1 pooled-v row

__device__ __forceinline__ float wave_reduce_sum(float v) {
    #pragma unroll
    for (int off = 32; off > 0; off >>= 1) v += __shfl_xor(v, off, 64);
    return v;
}
__device__ __forceinline__ float wave_reduce_max(float v) {
    #pragma unroll
    for (int off = 32; off > 0; off >>= 1) v = fmaxf(v, __shfl_xor(v, off, 64));
    return v;
}

// --- K1: fused independent precompute --------------------------------------
// blocks 0..127   : PET[d][n] generation (8 n-tiles x 16 j-groups)
// blocks 128..255 : LDS-tiled transpose Wk->WkT, Wv->WvT (8x8 tiles x 2 mats)
// block  256      : LayerNorm of query*scale (4 waves x 4 rows)
__global__ void k1_setup(const float* __restrict__ Wk, const float* __restrict__ Wv,
                         const float* __restrict__ query,
                         const float* __restrict__ ln_q_w, const float* __restrict__ ln_q_b,
                         float* __restrict__ PET, float* __restrict__ WkT,
                         float* __restrict__ WvT, float* __restrict__ q_ln, int N) {
    __shared__ float tile[64][65];
    int bx = blockIdx.x;
    int lane = threadIdx.x & 63;
    int w = threadIdx.x >> 6;

    if (bx < 128) {                       // --- PET ---
        int ntile = bx & 7, jg = bx >> 3;
        int n = ntile * 64 + lane;
        float p = (float)(N - 1 - n);     // reversed PE
        const float c = -logf(10000.f) / (float)DM;
        int jbase = jg * 16 + w * 4;
        #pragma unroll
        for (int u = 0; u < 4; ++u) {
            int j = jbase + u;
            float wj = expf((float)(2 * j) * c);
            float ang = p * wj;
            PET[(size_t)(2 * j) * N + n] = sinf(ang);
            PET[(size_t)(2 * j + 1) * N + n] = cosf(ang);
        }
    } else if (bx < 256) {                // --- transpose ---
        int t = bx - 128;
        const float* W = (t >> 6) ? Wv : Wk;
        float* WT = (t >> 6) ? WvT : WkT;
        int tl = t & 63;
        int te = tl >> 3, td = tl & 7;    // 8x8 tiles of 64x64
        #pragma unroll
        for (int i = 0; i < 16; ++i) {
            int el = w * 16 + i;
            tile[el][lane] = W[(size_t)(te * 64 + el) * DM + td * 64 + lane];
        }
        __syncthreads();
        #pragma unroll
        for (int i = 0; i < 16; ++i) {
            int dl = w * 16 + i;
            WT[(size_t)(td * 64 + dl) * DM + te * 64 + lane] = tile[lane][dl];
        }
    } else {                              // --- query LN ---
        const float scale = 22.627416997969522f;   // sqrt(512)
        for (int qi = 0; qi < 4; ++qi) {
            int q = w * 4 + qi;
            float vals[8], s = 0.f, s2 = 0.f;
            #pragma unroll
            for (int i = 0; i < 8; ++i) {
                float x = query[q * DM + i * 64 + lane] * scale;
                vals[i] = x; s += x; s2 += x * x;
            }
            s = wave_reduce_sum(s); s2 = wave_reduce_sum(s2);
            float m = s * (1.f / DM);
            float var = s2 * (1.f / DM) - m * m;
            float rstd = rsqrtf(var + 1e-5f);
            #pragma unroll
            for (int i = 0; i < 8; ++i) {
                int d = i * 64 + lane;
                q_ln[q * DM + d] = (vals[i] - m) * rstd * ln_q_w[d] + ln_q_b[d];
            }
        }
    }
}

// --- K2: qh[q][e] = q_ln[q] . Wq[e] + bq[e], one wave per output -----------
__global__ void k2_qh(const float* __restrict__ q_ln, const float* __restrict__ Wq,
                      const float* __restrict__ bq, float* __restrict__ qh) {
    int idx = blockIdx.x * 4 + (threadIdx.x >> 6);   // 0..8191
    int lane = threadIdx.x & 63;
    int q = idx >> 9, e = idx & 511;
    const float4* wr = (const float4*)(Wq + (size_t)e * DM);
    const float4* xr = (const float4*)(q_ln + (size_t)q * DM);
    float4 w0 = wr[lane * 2], w1 = wr[lane * 2 + 1];
    float4 x0 = xr[lane * 2], x1 = xr[lane * 2 + 1];
    float s = w0.x * x0.x + w0.y * x0.y + w0.z * x0.z + w0.w * x0.w
            + w1.x * x1.x + w1.y * x1.y + w1.z * x1.z + w1.w * x1.w;
    s = wave_reduce_sum(s);
    if (lane == 0) qh[q * DM + e] = s + bq[e];
}

// --- K3: qt[g][d] (g<16) and wv[d] (g=16) via contiguous WkT/WvT rows ------
//         A[g][d] = coeff * ln_lat_w[d]
__global__ void k3_qt(const float* __restrict__ qh, const float* __restrict__ WkT,
                      const float* __restrict__ Wo, const float* __restrict__ WvT,
                      const float* __restrict__ lnw,
                      float* __restrict__ qt, float* __restrict__ A,
                      float* __restrict__ wvout) {
    int idx = blockIdx.x * 4 + (threadIdx.x >> 6);   // 0..8703
    int lane = threadIdx.x & 63;
    int g = idx >> 9, d = idx & 511;
    const float4* wr;
    const float4* xr;
    if (g < NQ) {
        wr = (const float4*)(WkT + (size_t)d * DM);
        xr = (const float4*)(qh + (size_t)g * DM);
    } else {
        wr = (const float4*)(WvT + (size_t)d * DM);
        xr = (const float4*)Wo;
    }
    float4 w0 = wr[lane * 2], w1 = wr[lane * 2 + 1];
    float4 x0 = xr[lane * 2], x1 = xr[lane * 2 + 1];
    float s = w0.x * x0.x + w0.y * x0.y + w0.z * x0.z + w0.w * x0.w
            + w1.x * x1.x + w1.y * x1.y + w1.z * x1.z + w1.w * x1.w;
    s = wave_reduce_sum(s);
    if (lane == 0) {
        if (g < NQ) qt[g * DM + d] = s;
        else wvout[d] = s;
        A[g * DM + d] = s * lnw[d];
    }
}

// --- K4: peA rows (g<17), peS (g=17), peQ (g=18) + consts wave-tasks -------
// blocks 0..151: (g, ntile) with 4 waves splitting d into 128-chunks
// blocks 152..156: consts tasks (17 waves)
__global__ void k4_pea(const float* __restrict__ A, const float* __restrict__ PET,
                       const float* __restrict__ qt, const float* __restrict__ qh,
                       const float* __restrict__ wv, const float* __restrict__ lnb,
                       const float* __restrict__ bk, const float* __restrict__ Wo,
                       const float* __restrict__ bv,
                       float* __restrict__ peA, float* __restrict__ peS,
                       float* __restrict__ peQ, float* __restrict__ consts, int N) {
    __shared__ float red[4][64];
    int bx = blockIdx.x;
    int lane = threadIdx.x & 63;
    int w = threadIdx.x >> 6;

    if (bx < 152) {
        int g = bx >> 3, ntile = bx & 7;
        int n = ntile * 64 + lane;
        int d0 = w * 128;
        float acc = 0.f;
        if (g < NG) {
            for (int i = 0; i < 128; ++i) {
                int d = d0 + i;
                acc = fmaf(A[(size_t)g * DM + d], PET[(size_t)d * N + n], acc);
            }
        } else if (g == NG) {
            for (int i = 0; i < 128; ++i) acc += PET[(size_t)(d0 + i) * N + n];
        } else {
            for (int i = 0; i < 128; ++i) {
                float v = PET[(size_t)(d0 + i) * N + n];
                acc = fmaf(v, v, acc);
            }
        }
        red[w][lane] = acc;
        __syncthreads();
        if (w != 0) return;
        float tot = red[0][lane] + red[1][lane] + red[2][lane] + red[3][lane];
        if (g < NG) peA[(size_t)g * N + n] = tot;
        else if (g == NG) peS[n] = tot;
        else peQ[n] = tot;
    } else {
        int t = (bx - 152) * 4 + w;       // 0..19, valid 0..16
        if (t > NQ) return;
        if (t < NQ) {
            float sa = 0.f, sc = 0.f, qb = 0.f;
            #pragma unroll
            for (int i = 0; i < 8; ++i) {
                int d = i * 64 + lane;
                sa += A[t * DM + d];
                sc = fmaf(qt[t * DM + d], lnb[d], sc);
                qb = fmaf(qh[t * DM + d], bk[d], qb);
            }
            sa = wave_reduce_sum(sa);
            sc = wave_reduce_sum(sc);
            qb = wave_reduce_sum(qb);
            if (lane == 0) { consts[t] = sa; consts[16 + t] = sc + qb; }
        } else {
            float sa = 0.f, cv = 0.f, bvo = 0.f;
            #pragma unroll
            for (int i = 0; i < 8; ++i) {
                int d = i * 64 + lane;
                sa += A[NQ * DM + d];
                cv = fmaf(wv[d], lnb[d], cv);
                bvo = fmaf(Wo[d], bv[d], bvo);
            }
            sa = wave_reduce_sum(sa);
            cv = wave_reduce_sum(cv);
            bvo = wave_reduce_sum(bvo);
            if (lane == 0) { consts[32] = sa; consts[33] = cv + bvo; }
        }
    }
}

// --- K5: main streaming kernel: lane=column n, 4 waves split d -------------
__launch_bounds__(256, 4)
__global__ void main_kernel(const float* __restrict__ latents,
                            const float* __restrict__ PET,
                            const float* __restrict__ A,
                            const float* __restrict__ peA,
                            const float* __restrict__ peS,
                            const float* __restrict__ peQ,
                            const float* __restrict__ consts,
                            float* __restrict__ scores,
                            float* __restrict__ vbuf, int N) {
    int b = blockIdx.y;
    int lane = threadIdx.x & 63;
    int wv = threadIdx.x >> 6;
    int n = blockIdx.x * 64 + lane;
    const float scale = 22.627416997969522f;    // sqrt(512)

    int d0 = __builtin_amdgcn_readfirstlane(wv * (DM / 4));   // wave-uniform
    const float* lat = latents + (size_t)b * DM * N + (size_t)d0 * N + n;
    const float* pet = PET + (size_t)d0 * N + n;

    float acc[NG];
    #pragma unroll
    for (int i = 0; i < NG; ++i) acc[i] = 0.f;
    float S1 = 0.f, S2 = 0.f, Sx = 0.f;

    const int U = 8;                 // chunk size
    const int NC = (DM / 4) / U;     // 16 chunks of 8 d each
    float xb[2][U], pb[2][U];
    #pragma unroll
    for (int u = 0; u < U; ++u) {
        xb[0][u] = __builtin_nontemporal_load(&lat[(size_t)u * N]);
        pb[0][u] = pet[(size_t)u * N];
    }
    int cur = 0;
    for (int c = 0; c < NC; ++c) {
        int nxt = cur ^ 1;
        if (c + 1 < NC) {
            #pragma unroll
            for (int u = 0; u < U; ++u) {
                size_t dd = (size_t)((c + 1) * U + u) * N;
                xb[nxt][u] = __builtin_nontemporal_load(&lat[dd]);
                pb[nxt][u] = pet[dd];
            }
        }
        #pragma unroll
        for (int u = 0; u < U; ++u) {
            float x = xb[cur][u], pe = pb[cur][u];
            S1 += x; S2 = fmaf(x, x, S2); Sx = fmaf(x, pe, Sx);
            int d = d0 + c * U + u;              // fully scalar index
            #pragma unroll
            for (int q = 0; q < NG; ++q)
                acc[q] = fmaf(A[(size_t)q * DM + d], x, acc[q]);
        }
        cur = nxt;
    }

    __shared__ float red[4][NG + 3][64];
    red[wv][0][lane] = S1;
    red[wv][1][lane] = S2;
    red[wv][2][lane] = Sx;
    #pragma unroll
    for (int i = 0; i < NG; ++i) red[wv][3 + i][lane] = acc[i];
    __syncthreads();
    if (wv != 0) return;

    float tot[NG + 3];
    #pragma unroll
    for (int i = 0; i < NG + 3; ++i)
        tot[i] = red[0][i][lane] + red[1][i][lane] + red[2][i][lane] + red[3][i][lane];

    float s1 = tot[0], s2 = tot[1], sx = tot[2];
    float m = (scale * s1 + peS[n]) * (1.f / DM);
    float ex2 = (scale * scale * s2 + 2.f * scale * sx + peQ[n]) * (1.f / DM);
    float rstd = rsqrtf(ex2 - m * m + 1e-5f);

    float sumAv = consts[32], CvT = consts[33];
    float v = rstd * (scale * tot[3 + NQ] + peA[(size_t)NQ * N + n] - m * sumAv) + CvT;
    vbuf[(size_t)b * N + n] = v;

    const float isd = 0.044194173824159216f;    // 1/sqrt(512)
    #pragma unroll
    for (int q = 0; q < NQ; ++q) {
        float sc = (rstd * (scale * tot[3 + q] + peA[(size_t)q * N + n] - m * consts[q])
                    + consts[16 + q]) * isd;
        scores[((size_t)b * NQ + q) * N + n] = sc;
    }
}

// --- K6: softmax, 4 rows per block (wave per row) --------------------------
__global__ void softmax_kernel(const float* __restrict__ scores,
                               const float* __restrict__ vbuf,
                               const float* __restrict__ query_mask,
                               const float* __restrict__ bo,
                               float* __restrict__ out_logits,
                               float* __restrict__ out_attn, int N) {
    int r = blockIdx.x * 4 + (threadIdx.x >> 6);   // b*NQ + q
    int b = r >> 4;
    int lane = threadIdx.x & 63;
    float* attn_row = out_attn + (size_t)r * N;
    float qm = query_mask[r];
    if (qm == 0.f) {                    // fully masked row: uniform weights, wiped logits
        float u = 1.f / (float)N;
        for (int i = 0; i < N / 64; ++i) attn_row[i * 64 + lane] = u;
        if (lane == 0) out_logits[r] = bo[0];
        return;
    }
    const float* srow = scores + (size_t)r * N;
    float sv[8];
    float mx = -1e30f;
    for (int i = 0; i < N / 64; ++i) { sv[i] = srow[i * 64 + lane]; mx = fmaxf(mx, sv[i]); }
    mx = wave_reduce_max(mx);
    float sum = 0.f;
    for (int i = 0; i < N / 64; ++i) { sv[i] = expf(sv[i] - mx); sum += sv[i]; }
    sum = wave_reduce_sum(sum);
    float inv = 1.f / sum;
    const float* vrow = vbuf + (size_t)b * N;
    float lp = 0.f;
    for (int i = 0; i < N / 64; ++i) {
        float w = sv[i] * inv;
        attn_row[i * 64 + lane] = w;
        lp += w * vrow[i * 64 + lane];
    }
    lp = wave_reduce_sum(lp);
    if (lane == 0) out_logits[r] = lp + bo[0];
}

extern "C" void kernel_launch(void* const* d_in, const int* in_sizes, int n_in,
                              void* d_out, int out_size, void* d_ws, size_t ws_size,
                              hipStream_t stream) {
    const float* latents    = (const float*)d_in[0];
    const float* query_mask = (const float*)d_in[1];
    const float* query      = (const float*)d_in[2];
    const float* ln_lat_w   = (const float*)d_in[3];
    const float* ln_lat_b   = (const float*)d_in[4];
    const float* ln_q_w     = (const float*)d_in[5];
    const float* ln_q_b     = (const float*)d_in[6];
    const float* Wq         = (const float*)d_in[7];
    const float* bq         = (const float*)d_in[8];
    const float* Wk         = (const float*)d_in[9];
    const float* bk         = (const float*)d_in[10];
    const float* Wv         = (const float*)d_in[11];
    const float* bv         = (const float*)d_in[12];
    const float* Wo         = (const float*)d_in[13];
    const float* bo         = (const float*)d_in[14];

    int B = in_sizes[1] / NQ;
    int N = in_sizes[0] / (DM * B);

    float* ws = (float*)d_ws;
    size_t off = 0;
    float* PET    = ws + off; off += (size_t)DM * N;
    float* WkT    = ws + off; off += (size_t)DM * DM;
    float* WvT    = ws + off; off += (size_t)DM * DM;
    float* peS    = ws + off; off += N;
    float* peQ    = ws + off; off += N;
    float* q_ln   = ws + off; off += NQ * DM;
    float* qh     = ws + off; off += NQ * DM;
    float* qt     = ws + off; off += NQ * DM;
    float* A      = ws + off; off += NG * DM;
    float* wv     = ws + off; off += DM;
    float* peA    = ws + off; off += (size_t)NG * N;
    float* consts = ws + off; off += 64;
    float* scores = ws + off; off += (size_t)B * NQ * N;
    float* vbuf   = ws + off; off += (size_t)B * N;

    float* out_logits = (float*)d_out;
    float* out_attn   = out_logits + (size_t)B * NQ;

    k1_setup<<<257, 256, 0, stream>>>(Wk, Wv, query, ln_q_w, ln_q_b,
                                      PET, WkT, WvT, q_ln, N);
    k2_qh<<<NQ * DM / 4, 256, 0, stream>>>(q_ln, Wq, bq, qh);
    k3_qt<<<NG * DM / 4, 256, 0, stream>>>(qh, WkT, Wo, WvT, ln_lat_w, qt, A, wv);
    k4_pea<<<157, 256, 0, stream>>>(A, PET, qt, qh, wv, ln_lat_b, bk, Wo, bv,
                                    peA, peS, peQ, consts, N);
    dim3 gmain(N / 64, B);
    main_kernel<<<gmain, 256, 0, stream>>>(latents, PET, A, peA, peS, peQ, consts,
                                           scores, vbuf, N);
    softmax_kernel<<<B * NQ / 4, 256, 0, stream>>>(scores, vbuf, query_mask, bo,
                                                   out_logits, out_attn, N);
}